// Round 7
// baseline (402.144 us; speedup 1.0000x reference)
//
#include <hip/hip_runtime.h>
#include <hip/hip_bf16.h>
#include <math.h>

#define N_NODES 20000
#define N_EDGES 320000
#define IN_DIM 128
#define HID 256
#define HEADS 8
#define DH 32
#define LAYERS 3
#define NUM_GRAPHS 64
#define OUT_DIM 10
#define SLOPE 0.2f

typedef __bf16 bf16x8 __attribute__((ext_vector_type(8)));
typedef float f32x4 __attribute__((ext_vector_type(4)));

static __device__ __forceinline__ unsigned short f2bfbits(float v) {
    __bf16 b = (__bf16)v;
    return __builtin_bit_cast(unsigned short, b);
}
// unpack 8 bf16 (in a uint4) -> 8 fp32, exact
static __device__ __forceinline__ void unpack8(uint4 u, float* f) {
    unsigned p0 = u.x, p1 = u.y, p2 = u.z, p3 = u.w;
    f[0] = __builtin_bit_cast(float, p0 << 16);
    f[1] = __builtin_bit_cast(float, p0 & 0xffff0000u);
    f[2] = __builtin_bit_cast(float, p1 << 16);
    f[3] = __builtin_bit_cast(float, p1 & 0xffff0000u);
    f[4] = __builtin_bit_cast(float, p2 << 16);
    f[5] = __builtin_bit_cast(float, p2 & 0xffff0000u);
    f[6] = __builtin_bit_cast(float, p3 << 16);
    f[7] = __builtin_bit_cast(float, p3 & 0xffff0000u);
}

// async 16B global->LDS (DMA, wave-uniform LDS base + lane*16)
typedef const __attribute__((address_space(1))) unsigned int* as1_u32p;
typedef __attribute__((address_space(3))) unsigned int* as3_u32p;
static __device__ __forceinline__ void async_cp16(const unsigned short* g, unsigned short* l) {
    __builtin_amdgcn_global_load_lds((as1_u32p)g, (as3_u32p)l, 16, 0, 0);
}

// ---------------- utility kernels ----------------
__global__ void zero2_kernel(float* __restrict__ p1, int n1, float* __restrict__ p2, int n2) {
    int i = blockIdx.x * blockDim.x + threadIdx.x;
    if (i < n1) p1[i] = 0.f;
    int j = i - n1;
    if (j >= 0 && j < n2) p2[j] = 0.f;
}

// fused prep: feature cast (float4->bf16x4) + weight transpose/cast
#define CAST_N4 (N_NODES * IN_DIM / 4)
#define WTRANS_TOTAL (IN_DIM * HID + 6 * HID * HID)
#define PREP_TOTAL (CAST_N4 + WTRANS_TOTAL)
__global__ void prep_kernel(const float* __restrict__ feat,
                            const float* __restrict__ Win,
                            const float* __restrict__ Wsrc,
                            const float* __restrict__ Wdst,
                            unsigned short* __restrict__ featH,
                            unsigned short* __restrict__ WinT,
                            unsigned short* __restrict__ WT) {
    int idx = blockIdx.x * blockDim.x + threadIdx.x;
    if (idx < CAST_N4) {
        float4 v = ((const float4*)feat)[idx];
        ushort4 o;
        o.x = f2bfbits(v.x); o.y = f2bfbits(v.y);
        o.z = f2bfbits(v.z); o.w = f2bfbits(v.w);
        ((ushort4*)featH)[idx] = o;
    } else {
        int j = idx - CAST_N4;
        if (j < IN_DIM * HID) {
            int n = j / IN_DIM, k = j % IN_DIM;
            WinT[j] = f2bfbits(Win[k * HID + n]);
        } else if (j < WTRANS_TOTAL) {
            int r6 = j - IN_DIM * HID;
            int mat = r6 >> 16;
            int r = r6 & 65535;
            int n = r >> 8, k = r & 255;
            const float* base = (mat < 3) ? (Wsrc + (size_t)mat * 65536)
                                          : (Wdst + (size_t)(mat - 3) * 65536);
            WT[r6] = f2bfbits(base[k * 256 + n]);
        }
    }
}

// ---------------- CSR build (group edges by dst) ----------------
__global__ void count_kernel(const int* __restrict__ dst, int* __restrict__ cnt) {
    int e = blockIdx.x * blockDim.x + threadIdx.x;
    if (e < N_EDGES) atomicAdd(&cnt[dst[e]], 1);
}

// parallel single-block scan: 1024 threads x 20 counters each
#define SCAN_CHUNK 20
__global__ __launch_bounds__(1024) void scan_kernel(const int* __restrict__ cnt,
                                                    int* __restrict__ offs,
                                                    int* __restrict__ cursor) {
    __shared__ int wsum[16];
    int t = threadIdx.x;
    int beg = t * SCAN_CHUNK;

    int c[SCAN_CHUNK];
    int s = 0;
#pragma unroll
    for (int i = 0; i < SCAN_CHUNK; ++i) {
        int idx = beg + i;
        int x = (idx < N_NODES) ? cnt[idx] : 0;
        c[i] = x; s += x;
    }
    int v = s;
#pragma unroll
    for (int d = 1; d < 64; d <<= 1) {
        int u = __shfl_up(v, d, 64);
        if ((t & 63) >= d) v += u;
    }
    if ((t & 63) == 63) wsum[t >> 6] = v;
    __syncthreads();
    if (t < 16) {
        int wv = wsum[t];
#pragma unroll
        for (int d = 1; d < 16; d <<= 1) {
            int u = __shfl_up(wv, d, 64);
            if (t >= d) wv += u;
        }
        wsum[t] = wv;
    }
    __syncthreads();
    int waveoff = (t >> 6) ? wsum[(t >> 6) - 1] : 0;
    int run = waveoff + v - s;
#pragma unroll
    for (int i = 0; i < SCAN_CHUNK; ++i) {
        int idx = beg + i;
        if (idx < N_NODES) { offs[idx] = run; cursor[idx] = run; }
        run += c[i];
    }
    if (t == 0) offs[N_NODES] = wsum[15];
}

__global__ void fill_kernel(const int* __restrict__ src, const int* __restrict__ dst,
                            int* __restrict__ cursor, int* __restrict__ csr_src) {
    int e = blockIdx.x * blockDim.x + threadIdx.x;
    if (e < N_EDGES) {
        int p = atomicAdd(&cursor[dst[e]], 1);
        csr_src[p] = src[e];
    }
}

// ---------------- MFMA GEMM with async global->LDS staging ----------------
// C = (A_hi [+ A_lo])[M,K] @ B[K,N] + bias, B TRANSPOSED as BT[n][k] bf16.
// Staging via global_load_lds width=16 (wave-uniform LDS base + lane*16):
// rows unpadded (32 shorts = 64 B); 16B chunk XOR-swizzle c' = c ^ ((row>>1)&3)
// makes fragment ds_read_b128 exactly 2-way bank-aliased (free, m136).
// OUTMODE 1 (in-proj): C1f fp32 + bf16 hi/lo split. OUTMODE 2: bf16 C1,C2 only.
template <int SPLITA, int DUAL, int OUTMODE>
__global__ __launch_bounds__(256) void mfma_gemm(
    const unsigned short* __restrict__ Ah, const unsigned short* __restrict__ Al,
    const unsigned short* __restrict__ BT1, const float* __restrict__ bias1,
    float* __restrict__ C1f,
    unsigned short* __restrict__ O1a, unsigned short* __restrict__ O1b,
    const unsigned short* __restrict__ BT2, const float* __restrict__ bias2,
    unsigned short* __restrict__ O2,
    int M, int K, int N) {
    __shared__ __align__(16) unsigned short As_hi[128 * 32];
    __shared__ __align__(16) unsigned short As_lo[SPLITA ? 128 * 32 : 8];
    __shared__ __align__(16) unsigned short Bs1[64 * 32];
    __shared__ __align__(16) unsigned short Bs2[DUAL ? 64 * 32 : 8];

    const int t = threadIdx.x;
    const int wv = t >> 6, lane = t & 63, quad = lane >> 4, l15 = lane & 15;
    const int m0 = blockIdx.x * 128, n0 = blockIdx.y * 64;

    // staging slot math (slot = 16B chunk; A: 512 slots, B: 256 slots)
    const int sA0 = wv * 128 + lane, sA1 = sA0 + 64;
    const int sB = wv * 64 + lane;
    const int rA0 = sA0 >> 2, cA0 = (sA0 & 3) ^ ((rA0 >> 1) & 3);
    const int rA1 = sA1 >> 2, cA1 = (sA1 & 3) ^ ((rA1 >> 1) & 3);
    const int rB  = sB >> 2,  cB  = (sB & 3) ^ ((rB >> 1) & 3);
    int gmA0 = m0 + rA0; if (gmA0 >= M) gmA0 = M - 1;  // clamp: result rows discarded
    int gmA1 = m0 + rA1; if (gmA1 >= M) gmA1 = M - 1;
    const size_t offA0 = (size_t)gmA0 * K + cA0 * 8;
    const size_t offA1 = (size_t)gmA1 * K + cA1 * 8;
    const size_t offB  = (size_t)(n0 + rB) * K + cB * 8;
    unsigned short* ldsA0 = As_hi + wv * 1024;        // wave base (slots wv*128..)
    unsigned short* ldsA1 = As_hi + wv * 1024 + 512;
    unsigned short* ldsAl0 = As_lo + wv * 1024;
    unsigned short* ldsAl1 = As_lo + wv * 1024 + 512;
    unsigned short* ldsB1 = Bs1 + wv * 512;
    unsigned short* ldsB2 = Bs2 + wv * 512;

    f32x4 zero = {0.f, 0.f, 0.f, 0.f};
    f32x4 acc1[2][4], acc2[2][4];
#pragma unroll
    for (int mi = 0; mi < 2; ++mi)
#pragma unroll
        for (int t4 = 0; t4 < 4; ++t4) { acc1[mi][t4] = zero; acc2[mi][t4] = zero; }

    for (int k0 = 0; k0 < K; k0 += 32) {
        __syncthreads();  // previous iteration's LDS reads done
        async_cp16(Ah + offA0 + k0, ldsA0);
        async_cp16(Ah + offA1 + k0, ldsA1);
        if (SPLITA) {
            async_cp16(Al + offA0 + k0, ldsAl0);
            async_cp16(Al + offA1 + k0, ldsAl1);
        }
        async_cp16(BT1 + offB + k0, ldsB1);
        if (DUAL) async_cp16(BT2 + offB + k0, ldsB2);
        __syncthreads();  // drains vmcnt (compiler emits waitcnt before barrier)

        bf16x8 aHi[2], aLo[2];
#pragma unroll
        for (int mi = 0; mi < 2; ++mi) {
            int row = wv * 32 + mi * 16 + l15;
            int aoff = row * 32 + ((quad ^ ((row >> 1) & 3)) << 3);
            aHi[mi] = __builtin_bit_cast(bf16x8, *(const uint4*)(As_hi + aoff));
            if (SPLITA)
                aLo[mi] = __builtin_bit_cast(bf16x8, *(const uint4*)(As_lo + aoff));
        }
#pragma unroll
        for (int t4 = 0; t4 < 4; ++t4) {
            int brow = t4 * 16 + l15;
            int boff = brow * 32 + ((quad ^ ((brow >> 1) & 3)) << 3);
            bf16x8 b1 = __builtin_bit_cast(bf16x8, *(const uint4*)(Bs1 + boff));
#pragma unroll
            for (int mi = 0; mi < 2; ++mi) {
                acc1[mi][t4] = __builtin_amdgcn_mfma_f32_16x16x32_bf16(aHi[mi], b1, acc1[mi][t4], 0, 0, 0);
                if (SPLITA)
                    acc1[mi][t4] = __builtin_amdgcn_mfma_f32_16x16x32_bf16(aLo[mi], b1, acc1[mi][t4], 0, 0, 0);
            }
            if (DUAL) {
                bf16x8 b2 = __builtin_bit_cast(bf16x8, *(const uint4*)(Bs2 + boff));
#pragma unroll
                for (int mi = 0; mi < 2; ++mi) {
                    acc2[mi][t4] = __builtin_amdgcn_mfma_f32_16x16x32_bf16(aHi[mi], b2, acc2[mi][t4], 0, 0, 0);
                    if (SPLITA)
                        acc2[mi][t4] = __builtin_amdgcn_mfma_f32_16x16x32_bf16(aLo[mi], b2, acc2[mi][t4], 0, 0, 0);
                }
            }
        }
    }

    // epilogue (C/D: col=lane&15, row=quad*4+reg)
    float bia1[4], bia2[4];
#pragma unroll
    for (int t4 = 0; t4 < 4; ++t4) {
        bia1[t4] = bias1[n0 + t4 * 16 + l15];
        bia2[t4] = DUAL ? bias2[n0 + t4 * 16 + l15] : 0.f;
    }
#pragma unroll
    for (int mi = 0; mi < 2; ++mi) {
#pragma unroll
        for (int t4 = 0; t4 < 4; ++t4) {
            int gn = n0 + t4 * 16 + l15;
#pragma unroll
            for (int r = 0; r < 4; ++r) {
                int gm = m0 + wv * 32 + mi * 16 + quad * 4 + r;
                if (gm < M) {
                    float v = acc1[mi][t4][r] + bia1[t4];
                    if (OUTMODE == 1) {
                        C1f[(size_t)gm * N + gn] = v;
                        unsigned short hb = f2bfbits(v);
                        O1a[(size_t)gm * N + gn] = hb;
                        float hf = (float)__builtin_bit_cast(__bf16, hb);
                        O1b[(size_t)gm * N + gn] = f2bfbits(v - hf);
                    } else {
                        O1a[(size_t)gm * N + gn] = f2bfbits(v);
                        float v2 = acc2[mi][t4][r] + bia2[t4];
                        O2[(size_t)gm * N + gn] = f2bfbits(v2);
                    }
                }
            }
        }
    }
}

// ---------------- GATv2 aggregation (+ optional fused sum-pool) ----------------
// bf16 fs/fd tables; one HALF-wave (32 lanes) per node; block = 8 nodes exactly
// (20000 % 8 == 0 -> grid exact, no partial blocks). pool_mode: skip h write,
// block-level LDS-atomic per-graph accumulation + 256 global atomics
// (graph-boundary blocks fall back to direct atomics; gids are sorted).
__global__ __launch_bounds__(256) void gat_agg2(
    const unsigned short* __restrict__ fsb, const unsigned short* __restrict__ fdb,
    float* __restrict__ h, const int* __restrict__ offs,
    const int* __restrict__ csr_src, const float* __restrict__ attn_l,
    unsigned short* __restrict__ h_hi, unsigned short* __restrict__ h_lo,
    int write_split,
    const int* __restrict__ gid, float* __restrict__ hg, int pool_mode) {
    __shared__ float pacc[HID];
    __shared__ int guni;
    int tid = threadIdx.x;
    if (pool_mode) {
        pacc[tid] = 0.f;
        if (tid == 0) {
            int n0b = blockIdx.x * 8;
            guni = (gid[n0b] == gid[n0b + 7]) ? gid[n0b] : -1;
        }
        __syncthreads();
    }

    int node = (blockIdx.x * blockDim.x + tid) >> 5;
    int l32 = tid & 31;
    int dbase = l32 * 8;                           // 8 contiguous dims per lane
    int abase = (l32 >> 2) * DH + (l32 & 3) * 8;   // head = l32>>2 (4 lanes/head)

    float a[8];
#pragma unroll
    for (int j = 0; j < 8; ++j) a[j] = attn_l[abase + j];

    float fdv[8];
    unpack8(*(const uint4*)(fdb + (size_t)node * HID + dbase), fdv);

    float m = -INFINITY, ssum = 0.f;
    float acc[8];
#pragma unroll
    for (int j = 0; j < 8; ++j) acc[j] = 0.f;

    auto procU = [&](uint4 u) {
        float fsv[8];
        unpack8(u, fsv);
        float p = 0.f;
#pragma unroll
        for (int j = 0; j < 8; ++j) {
            float e = fsv[j] + fdv[j];
            e = e > 0.f ? e : SLOPE * e;
            p += e * a[j];
        }
        p += __shfl_xor(p, 1, 64);   // reduce over the 4 lanes of this head
        p += __shfl_xor(p, 2, 64);
        float mn = fmaxf(m, p);
        float corr = __expf(m - mn);  // m=-inf first edge -> corr=0
        float w = __expf(p - mn);
        ssum = ssum * corr + w;
#pragma unroll
        for (int j = 0; j < 8; ++j) acc[j] = acc[j] * corr + w * fsv[j];
        m = mn;
    };

    int beg = offs[node], end = offs[node + 1];
    int idx = beg;
    for (; idx + 4 <= end; idx += 4) {
        int sv0 = csr_src[idx];
        int sv1 = csr_src[idx + 1];
        int sv2 = csr_src[idx + 2];
        int sv3 = csr_src[idx + 3];
        uint4 u0 = *(const uint4*)(fsb + (size_t)sv0 * HID + dbase);
        uint4 u1 = *(const uint4*)(fsb + (size_t)sv1 * HID + dbase);
        uint4 u2 = *(const uint4*)(fsb + (size_t)sv2 * HID + dbase);
        uint4 u3 = *(const uint4*)(fsb + (size_t)sv3 * HID + dbase);
        procU(u0);
        procU(u1);
        procU(u2);
        procU(u3);
    }
    for (; idx < end; ++idx) {
        int sv = csr_src[idx];
        procU(*(const uint4*)(fsb + (size_t)sv * HID + dbase));
    }

    float inv = ssum > 0.f ? 1.f / ssum : 0.f;
    float4 hv0 = *(const float4*)(h + (size_t)node * HID + dbase);
    float4 hv1 = *(const float4*)(h + (size_t)node * HID + dbase + 4);
    float o[8];
    o[0] = fmaxf(acc[0] * inv + hv0.x, 0.f);
    o[1] = fmaxf(acc[1] * inv + hv0.y, 0.f);
    o[2] = fmaxf(acc[2] * inv + hv0.z, 0.f);
    o[3] = fmaxf(acc[3] * inv + hv0.w, 0.f);
    o[4] = fmaxf(acc[4] * inv + hv1.x, 0.f);
    o[5] = fmaxf(acc[5] * inv + hv1.y, 0.f);
    o[6] = fmaxf(acc[6] * inv + hv1.z, 0.f);
    o[7] = fmaxf(acc[7] * inv + hv1.w, 0.f);

    if (!pool_mode) {
        *(float4*)(h + (size_t)node * HID + dbase) = make_float4(o[0], o[1], o[2], o[3]);
        *(float4*)(h + (size_t)node * HID + dbase + 4) = make_float4(o[4], o[5], o[6], o[7]);
        if (write_split) {
            unsigned short hb[8], lb[8];
#pragma unroll
            for (int j = 0; j < 8; ++j) {
                hb[j] = f2bfbits(o[j]);
                float hf = (float)__builtin_bit_cast(__bf16, hb[j]);
                lb[j] = f2bfbits(o[j] - hf);
            }
            *(uint4*)(h_hi + (size_t)node * HID + dbase) = *(uint4*)hb;
            *(uint4*)(h_lo + (size_t)node * HID + dbase) = *(uint4*)lb;
        }
    } else {
        int g = gid[node];
        if (guni >= 0) {  // block-uniform branch
#pragma unroll
            for (int j = 0; j < 8; ++j) atomicAdd(&pacc[dbase + j], o[j]);
            __syncthreads();
            atomicAdd(&hg[(size_t)guni * HID + tid], pacc[tid]);
        } else {
#pragma unroll
            for (int j = 0; j < 8; ++j) atomicAdd(&hg[(size_t)g * HID + dbase + j], o[j]);
        }
    }
}

// ---------------- classifier: one block per graph ----------------
__global__ __launch_bounds__(256) void classifier_kernel(
    const float* __restrict__ hg,
    const float* __restrict__ Wc1, const float* __restrict__ bc1,
    const float* __restrict__ Wc2, const float* __restrict__ bc2,
    const float* __restrict__ Wc3, const float* __restrict__ bc3,
    float* __restrict__ out) {
    __shared__ float xin[HID];
    __shared__ float x1[HID];
    __shared__ float x2[HID / 2];
    int g = blockIdx.x, t = threadIdx.x;
    xin[t] = hg[(size_t)g * HID + t];
    __syncthreads();
    {
        float acc = bc1[t];
        for (int k = 0; k < HID; ++k) acc += xin[k] * Wc1[k * HID + t];
        x1[t] = fmaxf(acc, 0.f);
    }
    __syncthreads();
    if (t < HID / 2) {
        float acc = bc2[t];
        for (int k = 0; k < HID; ++k) acc += x1[k] * Wc2[k * (HID / 2) + t];
        x2[t] = fmaxf(acc, 0.f);
    }
    __syncthreads();
    if (t < OUT_DIM) {
        float acc = bc3[t];
        for (int k = 0; k < HID / 2; ++k) acc += x2[k] * Wc3[k * OUT_DIM + t];
        out[g * OUT_DIM + t] = acc;
    }
}

// ---------------- launch ----------------
extern "C" void kernel_launch(void* const* d_in, const int* in_sizes, int n_in,
                              void* d_out, int out_size, void* d_ws, size_t ws_size,
                              hipStream_t stream) {
    const float* feature = (const float*)d_in[0];
    const float* W_in   = (const float*)d_in[1];
    const float* b_in   = (const float*)d_in[2];
    const float* W_src  = (const float*)d_in[3];
    const float* b_src  = (const float*)d_in[4];
    const float* W_dst  = (const float*)d_in[5];
    const float* b_dst  = (const float*)d_in[6];
    const float* attn   = (const float*)d_in[7];
    const float* Wc1    = (const float*)d_in[8];
    const float* bc1    = (const float*)d_in[9];
    const float* Wc2    = (const float*)d_in[10];
    const float* bc2    = (const float*)d_in[11];
    const float* Wc3    = (const float*)d_in[12];
    const float* bc3    = (const float*)d_in[13];
    const int* src     = (const int*)d_in[14];
    const int* dst     = (const int*)d_in[15];
    const int* gid     = (const int*)d_in[16];
    float* out = (float*)d_out;

    char* w = (char*)d_ws;
    auto alloc = [&](size_t bytes) -> void* {
        void* p = (void*)w;
        w += (bytes + 255) & ~(size_t)255;
        return p;
    };
    float* h     = (float*)alloc((size_t)N_NODES * HID * 4);
    unsigned short* fsb = (unsigned short*)alloc((size_t)N_NODES * HID * 2);
    unsigned short* fdb = (unsigned short*)alloc((size_t)N_NODES * HID * 2);
    float* hg    = (float*)alloc((size_t)NUM_GRAPHS * HID * 4);
    int* cnt     = (int*)alloc((size_t)N_NODES * 4);
    int* offs    = (int*)alloc((size_t)(N_NODES + 1) * 4);
    int* cursor  = (int*)alloc((size_t)N_NODES * 4);
    int* csr_src = (int*)alloc((size_t)N_EDGES * 4);
    unsigned short* h_hi = (unsigned short*)alloc((size_t)N_NODES * HID * 2);
    unsigned short* h_lo = (unsigned short*)alloc((size_t)N_NODES * HID * 2);
    unsigned short* WinT = (unsigned short*)alloc((size_t)IN_DIM * HID * 2);
    unsigned short* WT   = (unsigned short*)alloc((size_t)6 * HID * HID * 2);
    unsigned short* featH = (unsigned short*)alloc((size_t)N_NODES * IN_DIM * 2);
    (void)alloc(4096);  // slack for clamped staging overreach

    // init (cnt + hg in one kernel)
    hipLaunchKernelGGL(zero2_kernel, dim3((N_NODES + NUM_GRAPHS * HID + 255) / 256), dim3(256),
                       0, stream, (float*)cnt, N_NODES, hg, NUM_GRAPHS * HID);

    // prep: feature cast + weight transposes
    hipLaunchKernelGGL(prep_kernel, dim3((PREP_TOTAL + 255) / 256), dim3(256), 0, stream,
                       feature, W_in, W_src, W_dst, featH, WinT, WT);

    // CSR build by dst
    hipLaunchKernelGGL(count_kernel, dim3((N_EDGES + 255) / 256), dim3(256), 0, stream, dst, cnt);
    hipLaunchKernelGGL(scan_kernel, dim3(1), dim3(1024), 0, stream, cnt, offs, cursor);
    hipLaunchKernelGGL(fill_kernel, dim3((N_EDGES + 255) / 256), dim3(256), 0, stream,
                       src, dst, cursor, csr_src);

    dim3 ggrid((N_NODES + 127) / 128, HID / 64);  // 157 x 4

    // input projection: h = feature @ W_in + b_in (bf16-exact inputs -> exact)
    hipLaunchKernelGGL((mfma_gemm<0, 0, 1>), ggrid, dim3(256), 0, stream,
                       featH, (const unsigned short*)nullptr,
                       WinT, b_in, h, h_hi, h_lo,
                       (const unsigned short*)nullptr, (const float*)nullptr,
                       (unsigned short*)nullptr,
                       N_NODES, IN_DIM, HID);

    // GATv2 layers (last layer fuses the sum-pool)
    for (int l = 0; l < LAYERS; ++l) {
        hipLaunchKernelGGL((mfma_gemm<1, 1, 2>), ggrid, dim3(256), 0, stream,
                           h_hi, h_lo,
                           WT + (size_t)l * HID * HID, b_src + (size_t)l * HID,
                           (float*)nullptr, fsb, (unsigned short*)nullptr,
                           WT + (size_t)(3 + l) * HID * HID, b_dst + (size_t)l * HID, fdb,
                           N_NODES, HID, HID);
        int last = (l == LAYERS - 1);
        hipLaunchKernelGGL(gat_agg2, dim3(N_NODES / 8), dim3(256), 0, stream,
                           fsb, fdb, h, offs, csr_src, attn + (size_t)l * HEADS * DH,
                           h_hi, h_lo, last ? 0 : 1,
                           gid, hg, last);
    }

    // classifier
    hipLaunchKernelGGL(classifier_kernel, dim3(NUM_GRAPHS), dim3(256), 0, stream,
                       hg, Wc1, bc1, Wc2, bc2, Wc3, bc3, out);
}